// Round 14
// baseline (476.052 us; speedup 1.0000x reference)
//
#include <hip/hip_runtime.h>
#include <math.h>

#define N_NODES 50000
#define N_EDGES 800000
#define EA (N_EDGES + N_NODES)   /* edges + self loops = 850000 */
#define HEADS 4
#define HID 64
#define NG 64
#define NEG_SLOPE 0.2f
#define SCAN_CHUNK 1024
#define NBLK ((N_NODES + SCAN_CHUNK - 1) / SCAN_CHUNK)   /* 49 */

typedef _Float16 f16x8 __attribute__((ext_vector_type(8)));
typedef float f32x4 __attribute__((ext_vector_type(4)));

__device__ inline float lrelu(float x) { return x > 0.f ? x : NEG_SLOPE * x; }

// MFMA 16x16x32 f16 operand fragment: elem j -> k = 16*(j>>2) + lq*4 + (j&3)
__device__ inline f16x8 ldfrag(const _Float16* __restrict__ p, int lq) {
    uint2 lo = *(const uint2*)(p + lq * 4);
    uint2 hi = *(const uint2*)(p + 16 + lq * 4);
    union { uint4 u; f16x8 v; } f;
    f.u = make_uint4(lo.x, lo.y, hi.x, hi.y);
    return f.v;
}

// ---------------- CSR build ----------------
__global__ void k_zero(int* __restrict__ deg, float* __restrict__ pooled,
                       float* __restrict__ cnt)
{
    int i = blockIdx.x * 256 + threadIdx.x;
    int st = gridDim.x * 256;
    for (int j = i; j < N_NODES; j += st) deg[j] = 0;
    if (i < NG * HID) pooled[i] = 0.f;
    if (i < NG) cnt[i] = 0.f;
}

__global__ void k_deg(const int* __restrict__ ei, int* __restrict__ deg)
{
    int e = blockIdx.x * 256 + threadIdx.x;
    if (e >= EA) return;
    int d = (e < N_EDGES) ? ei[N_EDGES + e] : e - N_EDGES;
    atomicAdd(&deg[d], 1);
}

__global__ __launch_bounds__(1024) void k_scan1(const int* __restrict__ deg,
        int* __restrict__ incl, int* __restrict__ blksum)
{
    __shared__ int sd[SCAN_CHUNK];
    int t = threadIdx.x;
    int i = blockIdx.x * SCAN_CHUNK + t;
    sd[t] = (i < N_NODES) ? deg[i] : 0;
    for (int off = 1; off < SCAN_CHUNK; off <<= 1) {
        __syncthreads();
        int u = (t >= off) ? sd[t - off] : 0;
        __syncthreads();
        sd[t] += u;
    }
    if (i < N_NODES) incl[i] = sd[t];
    if (t == SCAN_CHUNK - 1) blksum[blockIdx.x] = sd[t];
}

// ---------- scan2 + weight prep fused (1 block, 256 threads) ----------
// W1T[n][k] = W1[k][n]   (256x64 fp16)  — k_post1 B operand (k = input dim 0..63)
// W2P[n][k] = W2[k][n]   (64x256 fp16)  — gemm2 B operand
// va1s[k*4+h] = sum_c W1[k][h*64+c]*a1s[h][c]  (fp32, [k][h] for k_prep)
// va2s[k]     = sum_c W2[k][c]*a2s[c]          (fp32, plain)
__global__ __launch_bounds__(256) void k_scan2p(const int* __restrict__ blksum,
        int* __restrict__ blkoff, const float* __restrict__ W1,
        const float* __restrict__ a1s, const float* __restrict__ a1d,
        const float* __restrict__ W2, const float* __restrict__ a2s,
        const float* __restrict__ a2d,
        _Float16* __restrict__ W1T, _Float16* __restrict__ W2P,
        float* __restrict__ va1s, float* __restrict__ va1d,
        float* __restrict__ va2s, float* __restrict__ va2d)
{
    const int t = threadIdx.x;
    if (t == 0) {
        int acc = 0;
        for (int b = 0; b < NBLK; ++b) { blkoff[b] = acc; acc += blksum[b]; }
    }
    for (int i = t; i < 256 * 64; i += 256) {
        int n = i >> 6, k = i & 63;
        W1T[i] = (_Float16)W1[k * 256 + n];
    }
    for (int i = t; i < 64 * 256; i += 256) {
        int n = i >> 8, k = i & 255;
        W2P[i] = (_Float16)W2[k * 64 + n];
    }
    {
        int k = t >> 2, h = t & 3;
        float ss = 0.f, sd = 0.f;
        for (int c = 0; c < 64; ++c) {
            float wv = W1[k * 256 + h * 64 + c];
            ss = fmaf(wv, a1s[h * 64 + c], ss);
            sd = fmaf(wv, a1d[h * 64 + c], sd);
        }
        va1s[t] = ss;   // [k][h]
        va1d[t] = sd;
    }
    {
        float ss = 0.f, sd = 0.f;
        for (int c = 0; c < 64; ++c) {
            float wv = W2[t * 64 + c];
            ss = fmaf(wv, a2s[c], ss);
            sd = fmaf(wv, a2d[c], sd);
        }
        va2s[t] = ss;
        va2d[t] = sd;
    }
}

__global__ void k_scan3(const int* __restrict__ incl, const int* __restrict__ blkoff,
                        const int* __restrict__ deg, const int* __restrict__ batch,
                        int* __restrict__ rowptr, int* __restrict__ cursor,
                        float* __restrict__ cnt)
{
    int i = blockIdx.x * 256 + threadIdx.x;
    bool act = i < N_NODES;
    if (act) {
        int v = incl[i] + blkoff[i >> 10];
        rowptr[i + 1] = v;
        cursor[i] = v - deg[i];
        if (i == 0) rowptr[0] = 0;
    }
    int g = act ? batch[i] : -1;
    int lane = threadIdx.x & 63;
    int g0 = __shfl(g, 0, 64);
    if (__all(g == g0)) {
        if (lane == 0 && g0 >= 0) atomicAdd(&cnt[g0], 64.f);
    } else if (act) {
        atomicAdd(&cnt[g], 1.f);
    }
}

__global__ void k_fill(const int* __restrict__ ei, int* __restrict__ cursor,
                       int* __restrict__ csr_src)
{
    int e = blockIdx.x * 256 + threadIdx.x;
    if (e >= EA) return;
    int s, d;
    if (e < N_EDGES) { s = ei[e]; d = ei[N_EDGES + e]; }
    else { s = e - N_EDGES; d = s; }
    int pos = atomicAdd(&cursor[d], 1);
    csr_src[pos] = s;
}

// ---------- prep: wave per node: x -> fp16, exact fp32 conv1 scores ----------
__global__ __launch_bounds__(256) void k_prep(const float* __restrict__ x,
        const float* __restrict__ va1s, const float* __restrict__ va1d,
        _Float16* __restrict__ xh, float* __restrict__ e1s, float* __restrict__ e1d)
{
    const int lane = threadIdx.x & 63;
    const int w = threadIdx.x >> 6;
    const int n = blockIdx.x * 4 + w;
    if (n >= N_NODES) return;
    float xv = x[(size_t)n * 64 + lane];
    xh[(size_t)n * 64 + lane] = (_Float16)xv;
    float4 vs = ((const float4*)va1s)[lane];   // va1s[k=lane][0..3]
    float4 vd = ((const float4*)va1d)[lane];
    float s0 = xv * vs.x, s1 = xv * vs.y, s2 = xv * vs.z, s3 = xv * vs.w;
    float d0 = xv * vd.x, d1 = xv * vd.y, d2 = xv * vd.z, d3 = xv * vd.w;
    #pragma unroll
    for (int off = 32; off > 0; off >>= 1) {
        s0 += __shfl_down(s0, off, 64); s1 += __shfl_down(s1, off, 64);
        s2 += __shfl_down(s2, off, 64); s3 += __shfl_down(s3, off, 64);
        d0 += __shfl_down(d0, off, 64); d1 += __shfl_down(d1, off, 64);
        d2 += __shfl_down(d2, off, 64); d3 += __shfl_down(d3, off, 64);
    }
    if (lane == 0) {
        ((float4*)e1s)[n] = make_float4(s0, s1, s2, s3);
        ((float4*)e1d)[n] = make_float4(d0, d1, d2, d3);
    }
}

// ---------- aggr1: INPUT-space aggregation. wave per dst, 2B/lane x-gathers ----------
// agg[d][h*64+c] = (1/den_h) * sum_e alpha_e^h * x[s][c]   (fp16, normalized)
__global__ __launch_bounds__(256) void k_aggr1(const int* __restrict__ rowptr,
        const int* __restrict__ csr_src, const float* __restrict__ e1s,
        const float* __restrict__ e1d, const _Float16* __restrict__ xh,
        _Float16* __restrict__ agg)
{
    const int lane = threadIdx.x & 63;
    const int w = __builtin_amdgcn_readfirstlane(threadIdx.x >> 6);
    const int d = blockIdx.x * 4 + w;
    if (d >= N_NODES) return;
    const int beg = rowptr[d], end = rowptr[d + 1];
    const float4 edv = ((const float4*)e1d)[d];
    float a0 = 0.f, a1 = 0.f, a2 = 0.f, a3 = 0.f;
    float d0 = 0.f, d1 = 0.f, d2 = 0.f, d3 = 0.f;
    for (int jb = beg; jb < end; jb += 64) {
        int myj = jb + lane;
        int sv = 0;
        float px = 0.f, py = 0.f, pz = 0.f, pw = 0.f;
        if (myj < end) {
            sv = csr_src[myj];
            float4 q = ((const float4*)e1s)[sv];
            px = __expf(lrelu(q.x + edv.x));
            py = __expf(lrelu(q.y + edv.y));
            pz = __expf(lrelu(q.z + edv.z));
            pw = __expf(lrelu(q.w + edv.w));
        }
        int nj = end - jb; if (nj > 64) nj = 64;
        int njr = (nj + 15) & ~15;
        for (int j = 0; j < njr; j += 16) {
            #pragma unroll
            for (int k = 0; k < 16; ++k) {
                int s = __shfl(sv, j + k, 64);
                float p0 = __shfl(px, j + k, 64);
                float p1 = __shfl(py, j + k, 64);
                float p2 = __shfl(pz, j + k, 64);
                float p3 = __shfl(pw, j + k, 64);
                float xv = (float)xh[(size_t)s * 64 + lane];
                a0 = fmaf(p0, xv, a0);
                a1 = fmaf(p1, xv, a1);
                a2 = fmaf(p2, xv, a2);
                a3 = fmaf(p3, xv, a3);
                d0 += p0; d1 += p1; d2 += p2; d3 += p3;
            }
        }
    }
    _Float16* ad = agg + (size_t)d * 256;
    ad[lane]        = (_Float16)(a0 / d0);
    ad[64 + lane]   = (_Float16)(a1 / d1);
    ad[128 + lane]  = (_Float16)(a2 / d2);
    ad[192 + lane]  = (_Float16)(a3 / d3);
}

// ---------- post1: per-head MFMA (agg @ W1) + bias + ELU + conv2 scores ----------
__global__ __launch_bounds__(256) void k_post1(const _Float16* __restrict__ agg,
        const _Float16* __restrict__ W1T, const float* __restrict__ b1,
        const float* __restrict__ va2s, const float* __restrict__ va2d,
        _Float16* __restrict__ h1h, float* __restrict__ e2s_o,
        float* __restrict__ e2d_o)
{
    const int t = threadIdx.x;
    const int lane = t & 63, w = t >> 6;
    const int l15 = lane & 15, lq = lane >> 4;
    const int m0 = blockIdx.x * 64 + w * 16;
    const int mrow = m0 + l15;
    const int mc = mrow < N_NODES ? mrow : N_NODES - 1;
    const _Float16* arow = agg + (size_t)mc * 256;
    f16x8 af[8];
    #pragma unroll
    for (int ks = 0; ks < 8; ++ks) af[ks] = ldfrag(arow + ks * 32, lq);
    float es = 0.f, edd = 0.f;
    #pragma unroll
    for (int ct = 0; ct < 16; ++ct) {
        const int hh = ct >> 2;
        const _Float16* wrow = W1T + (size_t)(ct * 16 + l15) * 64;
        f16x8 wf0 = ldfrag(wrow, lq);
        f16x8 wf1 = ldfrag(wrow + 32, lq);
        f32x4 acc = {0.f, 0.f, 0.f, 0.f};
        acc = __builtin_amdgcn_mfma_f32_16x16x32_f16(wf0, af[2 * hh], acc, 0, 0, 0);
        acc = __builtin_amdgcn_mfma_f32_16x16x32_f16(wf1, af[2 * hh + 1], acc, 0, 0, 0);
        float4 bb = ((const float4*)b1)[ct * 4 + lq];
        float4 ssv = ((const float4*)va2s)[ct * 4 + lq];
        float4 ddv = ((const float4*)va2d)[ct * 4 + lq];
        float bbv[4] = {bb.x, bb.y, bb.z, bb.w};
        float sss[4] = {ssv.x, ssv.y, ssv.z, ssv.w};
        float ddd[4] = {ddv.x, ddv.y, ddv.z, ddv.w};
        union { uint2 u2; _Float16 e[4]; } o;
        #pragma unroll
        for (int j = 0; j < 4; ++j) {
            float v = acc[j] + bbv[j];
            v = v > 0.f ? v : __expf(v) - 1.f;
            o.e[j] = (_Float16)v;
            es  = fmaf(v, sss[j], es);
            edd = fmaf(v, ddd[j], edd);
        }
        if (mrow < N_NODES)
            *(uint2*)(h1h + (size_t)mrow * 256 + ct * 16 + lq * 4) = o.u2;
    }
    #pragma unroll
    for (int off = 16; off <= 32; off <<= 1) {
        es  += __shfl_down(es, off, 64);
        edd += __shfl_down(edd, off, 64);
    }
    if (lq == 0 && mrow < N_NODES) { e2s_o[mrow] = es; e2d_o[mrow] = edd; }
}

// ---------- conv2 GEMM via MFMA (plain k-order) ----------
__global__ __launch_bounds__(256) void k_gemm2(const _Float16* __restrict__ h1h,
        const _Float16* __restrict__ W2P, _Float16* __restrict__ xp2h)
{
    const int t = threadIdx.x;
    const int lane = t & 63, w = t >> 6;
    const int l15 = lane & 15, lq = lane >> 4;
    const int m0 = blockIdx.x * 64 + w * 16;
    const int mrow = m0 + l15;
    const _Float16* arow = h1h + (size_t)(m0 + l15) * 256;
    f16x8 af[8];
    #pragma unroll
    for (int ks = 0; ks < 8; ++ks) af[ks] = ldfrag(arow + ks * 32, lq);
    #pragma unroll
    for (int ct = 0; ct < 4; ++ct) {
        const _Float16* wrow = W2P + (size_t)(ct * 16 + l15) * 256;
        f32x4 acc = {0.f, 0.f, 0.f, 0.f};
        #pragma unroll
        for (int ks = 0; ks < 8; ++ks) {
            f16x8 wf = ldfrag(wrow + ks * 32, lq);
            acc = __builtin_amdgcn_mfma_f32_16x16x32_f16(wf, af[ks], acc, 0, 0, 0);
        }
        if (mrow < N_NODES) {
            union { uint2 u2; _Float16 e[4]; } o;
            o.e[0]=(_Float16)acc[0]; o.e[1]=(_Float16)acc[1];
            o.e[2]=(_Float16)acc[2]; o.e[3]=(_Float16)acc[3];
            *(uint2*)(xp2h + (size_t)mrow * 64 + ct * 16 + lq * 4) = o.u2;
        }
    }
}

// ---------- aggr2: wave per dst, 2B/lane gathers, unroll 16, fused mean-pool ----------
__global__ __launch_bounds__(256) void k_aggr2(const int* __restrict__ rowptr,
        const int* __restrict__ csr_src, const float* __restrict__ e2s,
        const float* __restrict__ e2d, const _Float16* __restrict__ xp2h,
        const float* __restrict__ b2, const int* __restrict__ batch,
        float* __restrict__ pooled)
{
    const int lane = threadIdx.x & 63;
    const int w = __builtin_amdgcn_readfirstlane(threadIdx.x >> 6);
    const int d = blockIdx.x * 4 + w;
    if (d >= N_NODES) return;
    const int beg = rowptr[d], end = rowptr[d + 1];
    const float edv = e2d[d];
    float acc = 0.f, den = 0.f;
    for (int jb = beg; jb < end; jb += 64) {
        int myj = jb + lane;
        int sv = 0;
        float p = 0.f;
        if (myj < end) {
            sv = csr_src[myj];
            p = __expf(lrelu(e2s[sv] + edv));
        }
        int nj = end - jb; if (nj > 64) nj = 64;
        int njr = (nj + 15) & ~15;
        for (int j = 0; j < njr; j += 16) {
            #pragma unroll
            for (int k = 0; k < 16; ++k) {
                int s = __shfl(sv, j + k, 64);
                float pv = __shfl(p, j + k, 64);
                acc = fmaf(pv, (float)xp2h[(size_t)s * 64 + lane], acc);
                den += pv;
            }
        }
    }
    float val = acc / den + b2[lane];
    int g = batch[d];
    atomicAdd(&pooled[g * 64 + lane], val);
}

__global__ void k_mlp(const float* __restrict__ pooled, const float* __restrict__ cnt,
                      const float* __restrict__ Wh1, const float* __restrict__ bh1,
                      const float* __restrict__ Wh2, const float* __restrict__ bh2,
                      float* __restrict__ out)
{
    int g = threadIdx.x;   // 64 threads
    float inv = 1.f / fmaxf(cnt[g], 1.f);
    float p[64];
    #pragma unroll
    for (int c = 0; c < 64; ++c) p[c] = pooled[g * 64 + c] * inv;
    float acc2 = bh2[0];
    for (int j = 0; j < 16; ++j) {
        float z = bh1[j];
        #pragma unroll
        for (int c = 0; c < 64; ++c) z = fmaf(p[c], Wh1[c * 16 + j], z);
        z = fmaxf(z, 0.f);
        acc2 = fmaf(z, Wh2[j], acc2);
    }
    out[g] = 1.f / (1.f + expf(-acc2));
}

extern "C" void kernel_launch(void* const* d_in, const int* in_sizes, int n_in,
                              void* d_out, int out_size, void* d_ws, size_t ws_size,
                              hipStream_t stream)
{
    const float* x      = (const float*)d_in[0];
    const int*   ei     = (const int*)d_in[1];
    const int*   batch  = (const int*)d_in[2];
    const float* W1     = (const float*)d_in[3];
    const float* a1s    = (const float*)d_in[4];
    const float* a1d    = (const float*)d_in[5];
    const float* b1     = (const float*)d_in[6];
    const float* W2     = (const float*)d_in[7];
    const float* a2s    = (const float*)d_in[8];
    const float* a2d    = (const float*)d_in[9];
    const float* b2     = (const float*)d_in[10];
    const float* Wh1    = (const float*)d_in[11];
    const float* bh1    = (const float*)d_in[12];
    const float* Wh2    = (const float*)d_in[13];
    const float* bh2    = (const float*)d_in[14];
    float* out = (float*)d_out;

    float* ws = (float*)d_ws;
    size_t off = 0;
    _Float16* xh   = (_Float16*)(ws + off); off += (size_t)N_NODES * 32;         // N*64 fp16
    _Float16* agg  = (_Float16*)(ws + off); off += (size_t)(N_NODES + 64) * 128; // N*256 fp16, padded
    _Float16* h1h  = (_Float16*)(ws + off); off += (size_t)(N_NODES + 64) * 128; // padded
    float* e1s    = ws + off; off += (size_t)N_NODES * 4;
    float* e1d    = ws + off; off += (size_t)N_NODES * 4;
    float* e2s    = ws + off; off += N_NODES;
    float* e2d    = ws + off; off += N_NODES;
    _Float16* xp2h = (_Float16*)(ws + off); off += (size_t)N_NODES * 32;         // N*64 fp16
    _Float16* W1T  = (_Float16*)(ws + off); off += 8192;
    _Float16* W2P  = (_Float16*)(ws + off); off += 8192;
    float* va1s   = ws + off; off += 256;
    float* va1d   = ws + off; off += 256;
    float* va2s   = ws + off; off += 256;
    float* va2d   = ws + off; off += 256;
    float* pooled = ws + off; off += NG * HID;
    float* cnt    = ws + off; off += NG;
    int* rowptr   = (int*)(ws + off); off += N_NODES + 2;
    int* cursor   = (int*)(ws + off); off += N_NODES;
    int* csr_src  = (int*)(ws + off); off += EA;
    int* blksum   = (int*)(ws + off); off += NBLK;
    int* blkoff   = (int*)(ws + off); off += NBLK;
    // deg/incl alias agg region (agg first written by k_aggr1; CSR build done by then)
    int* deg  = (int*)agg;
    int* incl = deg + N_NODES;

    const int BE = (EA + 255) / 256;
    const int BN = (N_NODES + 255) / 256;
    const int BW = (N_NODES + 3) / 4;      // wave-per-node grids
    const int BG = (N_NODES + 63) / 64;    // 64-row MFMA blocks

    hipLaunchKernelGGL(k_zero,   dim3(64),   dim3(256),  0, stream, deg, pooled, cnt);
    hipLaunchKernelGGL(k_deg,    dim3(BE),   dim3(256),  0, stream, ei, deg);
    hipLaunchKernelGGL(k_scan1,  dim3(NBLK), dim3(1024), 0, stream, deg, incl, blksum);
    hipLaunchKernelGGL(k_scan2p, dim3(1),    dim3(256),  0, stream,
                       blksum, blkoff, W1, a1s, a1d, W2, a2s, a2d,
                       W1T, W2P, va1s, va1d, va2s, va2d);
    hipLaunchKernelGGL(k_scan3,  dim3(BN),   dim3(256),  0, stream,
                       incl, blkoff, deg, batch, rowptr, cursor, cnt);
    hipLaunchKernelGGL(k_fill,   dim3(BE),   dim3(256),  0, stream, ei, cursor, csr_src);

    hipLaunchKernelGGL(k_prep,   dim3(BW),   dim3(256),  0, stream,
                       x, va1s, va1d, xh, e1s, e1d);
    hipLaunchKernelGGL(k_aggr1,  dim3(BW),   dim3(256),  0, stream,
                       rowptr, csr_src, e1s, e1d, xh, agg);
    hipLaunchKernelGGL(k_post1,  dim3(BG),   dim3(256),  0, stream,
                       agg, W1T, b1, va2s, va2d, h1h, e2s, e2d);
    hipLaunchKernelGGL(k_gemm2,  dim3(BG),   dim3(256),  0, stream, h1h, W2P, xp2h);
    hipLaunchKernelGGL(k_aggr2,  dim3(BW),   dim3(256),  0, stream,
                       rowptr, csr_src, e2s, e2d, xp2h, b2, batch, pooled);

    hipLaunchKernelGGL(k_mlp, dim3(1), dim3(64), 0, stream,
                       pooled, cnt, Wh1, bh1, Wh2, bh2, out);
}